// Round 6
// baseline (1437.251 us; speedup 1.0000x reference)
//
#include <hip/hip_runtime.h>

#define Bsz  256
#define Tlen 2048
#define Hdim 128

typedef __fp16 hf2 __attribute__((ext_vector_type(2)));
typedef __fp16 hf8 __attribute__((ext_vector_type(8)));
typedef float  f32x4 __attribute__((ext_vector_type(4)));

// Raw-HW transcendentals (VOP1, ~1 ulp). R12-verified win.
__device__ __forceinline__ float fexp2_(float x) {
    float r; asm("v_exp_f32 %0, %1" : "=v"(r) : "v"(x)); return r;
}
__device__ __forceinline__ float frcp_(float x) {
    float r; asm("v_rcp_f32 %0, %1" : "=v"(r) : "v"(x)); return r;
}

// pack 8 consecutive f32 into a v8f16 MFMA fragment slice
__device__ __forceinline__ hf8 pack8(const float* p) {
    union { hf2 h2[4]; hf8 h8; } u;
    u.h2[0] = __builtin_amdgcn_cvt_pkrtz(p[0], p[1]);
    u.h2[1] = __builtin_amdgcn_cvt_pkrtz(p[2], p[3]);
    u.h2[2] = __builtin_amdgcn_cvt_pkrtz(p[4], p[5]);
    u.h2[3] = __builtin_amdgcn_cvt_pkrtz(p[6], p[7]);
    return u.h8;
}
__device__ __forceinline__ hf8 bch8(float4 v) { return __builtin_bit_cast(hf8, v); }

#define MFMA(D, A, B) D = __builtin_amdgcn_mfma_f32_16x16x32_f16(A, B, D, 0, 0, 0)

struct Smem {
    float  x[2][Tlen];      // staged input rows (2 batch rows per block)
    float  xh[2][Tlen];     // staged xh outputs
    __fp16 h[2][2][Hdim];   // [t-parity][row][unit] hidden state (f16)
};

// grid = 128 blocks (TWO batch rows each), block = 512 threads (8 waves).
// R29 = R28 champion (16 MFMA/wave/row, uniform-A, weights AGPR-native,
// one barrier/step, setprio antiphase) x 2 interleaved batch rows.
// R28 post-mortem: setprio antiphase WORKED (935->894, MfmaUtil 50%), but
// pipes still nearly SUM (569 MFMA + 438 VALU of 1134 cyc/step): the
// per-step barrier resyncs the waves, and within one wave the 280-cyc
// MFMA issue and 219-cyc tail are serial (in-order issue, true deps).
// Fix: interleave a SECOND independent batch row in the same wave:
//   issue MFMA(row a) x16 -> issue MFMA(row b) x16 -> tail(a) -> tail(b)
// tail(a) executes under row b's MFMA pipe drain (in-wave software
// pipelining); A-read latency + barrier amortize over 2 rows; weights
// (AGPR) shared. Floor: max(64x19.4 MFMA-pipe, VALU+residual) + sync
// ~= 1350-1500 cyc / double-step = 675-750 cyc/row vs 1134 today.
// Session ledger: R24 fc->VALU -21% | R25 reorder flat | R26 diet flat |
// R27 16->12 MFMA -5% (slack absorbed it) | R28 setprio +4%.
// Layouts (R18-R21 HW-verified): B: lane l reg j = W[tile*16+(l&15)]
// [c*32+(l>>4)*8+j]; D: col = lane&15, reg 0 valid on all lanes (uniform A).
__global__ __launch_bounds__(512, 2)
void rnn_imp_kernel(const float* __restrict__ x,     // [B, T] (I=1)
                    const float* __restrict__ Wih,   // [384]
                    const float* __restrict__ Whh,   // [384, 128] gate-major (r,z,n)
                    const float* __restrict__ bih,   // [384]
                    const float* __restrict__ bhh,   // [384]
                    const float* __restrict__ Wfc,   // [128]
                    const float* __restrict__ bfc,   // [1]
                    float* __restrict__ out_newin,   // [T, B]
                    float* __restrict__ out_pred)    // [B, T-1]
{
    __shared__ __align__(128) Smem sm;

    const int tid  = threadIdx.x;
    const int b0   = blockIdx.x * 2;         // first batch row
    const int b1   = b0 + 1;                 // second batch row
    const int wave = tid >> 6;
    const int lane = tid & 63;
    const int m    = lane & 15;      // B/D column = unit-in-tile
    const int q    = lane >> 4;      // k-subchunk

    // stage both x rows (coalesced)
    for (int i = tid; i < Tlen; i += 512) {
        sm.x[0][i] = x[b0 * Tlen + i];
        sm.x[1][i] = x[b1 * Tlen + i];
    }

    // ---- B fragments: W^T tiles (consumed only by MFMA -> AGPR-native;
    //      SHARED by both rows) ----
    const int r0 = wave * 16 + m;            // unit row, gate r
    const int r1 = r0 + 128;                 // gate z
    const int r2 = r0 + 256;                 // gate n
    const int ko = q * 8;
    hf8 Br0, Br1, Br2, Br3, Bz0, Bz1, Bz2, Bz3,
        Bn0, Bn1, Bn2, Bn3, Bf0, Bf1, Bf2, Bf3;
    Br0 = pack8(Whh + r0 * Hdim + 0  + ko);  Br1 = pack8(Whh + r0 * Hdim + 32 + ko);
    Br2 = pack8(Whh + r0 * Hdim + 64 + ko);  Br3 = pack8(Whh + r0 * Hdim + 96 + ko);
    Bz0 = pack8(Whh + r1 * Hdim + 0  + ko);  Bz1 = pack8(Whh + r1 * Hdim + 32 + ko);
    Bz2 = pack8(Whh + r1 * Hdim + 64 + ko);  Bz3 = pack8(Whh + r1 * Hdim + 96 + ko);
    Bn0 = pack8(Whh + r2 * Hdim + 0  + ko);  Bn1 = pack8(Whh + r2 * Hdim + 32 + ko);
    Bn2 = pack8(Whh + r2 * Hdim + 64 + ko);  Bn3 = pack8(Whh + r2 * Hdim + 96 + ko);
    // Wfc in ALL columns: every lane's D3 reg 0 = xp
    Bf0 = pack8(Wfc + 0  + ko);  Bf1 = pack8(Wfc + 32 + ko);
    Bf2 = pack8(Wfc + 64 + ko);  Bf3 = pack8(Wfc + 96 + ko);

    // gate constants for this lane's column unit (valid on all lanes)
    const int ug = wave * 16 + m;
    const float wih_r = Wih[ug], wih_z = Wih[ug + 128], wih_n = Wih[ug + 256];
    const float bb_r = bih[ug]       + bhh[ug];
    const float bb_z = bih[ug + 128] + bhh[ug + 128];
    const float bi_n = bih[ug + 256];
    const float bh_n = bhh[ug + 256];
    const float bfc0 = bfc[0];

    // pre-scaled constants: fold log2e factors out of the per-step chain
    const float kNL2E = -1.44269504f;            // -log2(e)
    const float kP2L2E = 2.88539008f;            // 2*log2(e)
    const float wr_s  = kNL2E * wih_r;
    const float wz_s  = kNL2E * wih_z;
    const float wn_s  = kP2L2E * wih_n;
    const float bn_s  = kP2L2E * bi_n;
    // bias-seeded MFMA C operands (reg 0 is the one consumed)
    const f32x4 C_R = {bb_r, bb_r, bb_r, bb_r};
    const f32x4 C_Z = {bb_z, bb_z, bb_z, bb_z};
    const f32x4 C_N = {bh_n, bh_n, bh_n, bh_n};
    const f32x4 C_F = {bfc0, bfc0, bfc0, bfc0};

    __syncthreads();                         // sm.x visible

    // ---- peeled t = 0 (both rows): h = 0 => D = C-seed exactly; pure VALU
    float h_old_a, h_old_b;
    {
        float x0a = sm.x[0][0];
        float x0b = sm.x[1][0];

        float ra = frcp_(1.0f + fexp2_(fmaf(kNL2E, bb_r, wr_s * x0a)));
        float za = frcp_(1.0f + fexp2_(fmaf(kNL2E, bb_z, wz_s * x0a)));
        float npa = frcp_(fexp2_(fmaf(kP2L2E * ra, bh_n, fmaf(wn_s, x0a, bn_s))) + 1.0f);
        float wa = 1.0f - za;
        h_old_a = fmaf(-2.0f * wa, npa, wa);

        float rb = frcp_(1.0f + fexp2_(fmaf(kNL2E, bb_r, wr_s * x0b)));
        float zb = frcp_(1.0f + fexp2_(fmaf(kNL2E, bb_z, wz_s * x0b)));
        float npb = frcp_(fexp2_(fmaf(kP2L2E * rb, bh_n, fmaf(wn_s, x0b, bn_s))) + 1.0f);
        float wb = 1.0f - zb;
        h_old_b = fmaf(-2.0f * wb, npb, wb);

        if (lane < 16) {
            sm.h[1][0][ug] = (__fp16)h_old_a;
            sm.h[1][1][ug] = (__fp16)h_old_b;
        }
        // sm.xh[*][0] never consumed (pred uses xh[1..]; newin i=0 is raw x)
    }
    __syncthreads();

#pragma unroll 1
    for (int t = 1; t < Tlen; ++t) {
        // A fragments for BOTH rows (uniform-address broadcast reads);
        // row b's read latency hides under row a's MFMA issue
        const float4* hpa = (const float4*)sm.h[t & 1][0];
        const float4* hpb = (const float4*)sm.h[t & 1][1];
        hf8 Aa0 = bch8(hpa[0 * 4 + q]);
        hf8 Aa1 = bch8(hpa[1 * 4 + q]);
        hf8 Aa2 = bch8(hpa[2 * 4 + q]);
        hf8 Aa3 = bch8(hpa[3 * 4 + q]);
        hf8 Ab0 = bch8(hpb[0 * 4 + q]);
        hf8 Ab1 = bch8(hpb[1 * 4 + q]);
        hf8 Ab2 = bch8(hpb[2 * 4 + q]);
        hf8 Ab3 = bch8(hpb[3 * 4 + q]);

        float xta = sm.x[0][t];
        float xtb = sm.x[1][t];

        // ---- all 32 MFMAs issued back-to-back at raised priority:
        // row a's tail dependencies retire during row b's issue ----
        __builtin_amdgcn_s_setprio(1);

        f32x4 D3a = __builtin_amdgcn_mfma_f32_16x16x32_f16(Aa0, Bf0, C_F, 0, 0, 0);
        f32x4 D0a = __builtin_amdgcn_mfma_f32_16x16x32_f16(Aa0, Br0, C_R, 0, 0, 0);
        MFMA(D3a, Aa1, Bf1); MFMA(D0a, Aa1, Br1);
        MFMA(D3a, Aa2, Bf2); MFMA(D0a, Aa2, Br2);
        MFMA(D3a, Aa3, Bf3); MFMA(D0a, Aa3, Br3);
        f32x4 D1a = __builtin_amdgcn_mfma_f32_16x16x32_f16(Aa0, Bz0, C_Z, 0, 0, 0);
        f32x4 D2a = __builtin_amdgcn_mfma_f32_16x16x32_f16(Aa0, Bn0, C_N, 0, 0, 0);
        MFMA(D1a, Aa1, Bz1); MFMA(D2a, Aa1, Bn1);
        MFMA(D1a, Aa2, Bz2); MFMA(D2a, Aa2, Bn2);
        MFMA(D1a, Aa3, Bz3); MFMA(D2a, Aa3, Bn3);

        f32x4 D3b = __builtin_amdgcn_mfma_f32_16x16x32_f16(Ab0, Bf0, C_F, 0, 0, 0);
        f32x4 D0b = __builtin_amdgcn_mfma_f32_16x16x32_f16(Ab0, Br0, C_R, 0, 0, 0);
        MFMA(D3b, Ab1, Bf1); MFMA(D0b, Ab1, Br1);
        MFMA(D3b, Ab2, Bf2); MFMA(D0b, Ab2, Br2);
        MFMA(D3b, Ab3, Bf3); MFMA(D0b, Ab3, Br3);
        f32x4 D1b = __builtin_amdgcn_mfma_f32_16x16x32_f16(Ab0, Bz0, C_Z, 0, 0, 0);
        f32x4 D2b = __builtin_amdgcn_mfma_f32_16x16x32_f16(Ab0, Bn0, C_N, 0, 0, 0);
        MFMA(D1b, Ab1, Bz1); MFMA(D2b, Ab1, Bn1);
        MFMA(D1b, Ab2, Bz2); MFMA(D2b, Ab2, Bn2);
        MFMA(D1b, Ab3, Bz3); MFMA(D2b, Ab3, Bn3);

        __builtin_amdgcn_s_setprio(0);       // tails run at low priority

        // ---- tail row a (overlaps row b's MFMA pipe drain) ----
        float xha  = D3a[0];
        float cura = (xta == 128.0f) ? xha : xta;
        float pra  = wr_s * cura;
        float pza  = wz_s * cura;
        float ana  = fmaf(wn_s, cura, bn_s);
        float ra   = frcp_(1.0f + fexp2_(fmaf(kNL2E, D0a[0], pra)));
        float rsa  = kP2L2E * ra;
        float za   = frcp_(1.0f + fexp2_(fmaf(kNL2E, D1a[0], pza)));
        float npa  = frcp_(fexp2_(fmaf(rsa, D2a[0], ana)) + 1.0f);
        float wa   = 1.0f - za;
        float m2wa = -2.0f * wa;
        float hza  = fmaf(za, h_old_a, wa);
        float hna  = fmaf(m2wa, npa, hza);
        h_old_a = hna;

        // ---- tail row b ----
        float xhb  = D3b[0];
        float curb = (xtb == 128.0f) ? xhb : xtb;
        float prb  = wr_s * curb;
        float pzb  = wz_s * curb;
        float anb  = fmaf(wn_s, curb, bn_s);
        float rb   = frcp_(1.0f + fexp2_(fmaf(kNL2E, D0b[0], prb)));
        float rsb  = kP2L2E * rb;
        float zb   = frcp_(1.0f + fexp2_(fmaf(kNL2E, D1b[0], pzb)));
        float npb  = frcp_(fexp2_(fmaf(rsb, D2b[0], anb)) + 1.0f);
        float wb   = 1.0f - zb;
        float m2wb = -2.0f * wb;
        float hzb  = fmaf(zb, h_old_b, wb);
        float hnb  = fmaf(m2wb, npb, hzb);
        h_old_b = hnb;

        if (lane < 16) {
            sm.h[(t + 1) & 1][0][ug] = (__fp16)hna;
            sm.h[(t + 1) & 1][1][ug] = (__fp16)hnb;
        }
        if (tid == 0) {
            sm.xh[0][t] = xha;
            sm.xh[1][t] = xhb;
        }
        __syncthreads();
    }

    // bulk flush both rows; cur reconstructed from pristine x + xh
    for (int i = tid; i < Tlen; i += 512) {
        float xa = sm.x[0][i];
        float xb = sm.x[1][i];
        out_newin[i * Bsz + b0] = ((xa == 128.0f) && (i != 0)) ? sm.xh[0][i] : xa;
        out_newin[i * Bsz + b1] = ((xb == 128.0f) && (i != 0)) ? sm.xh[1][i] : xb;
    }
    for (int i = tid; i < Tlen - 1; i += 512) {
        out_pred[b0 * (Tlen - 1) + i] = sm.xh[0][i + 1];
        out_pred[b1 * (Tlen - 1) + i] = sm.xh[1][i + 1];
    }
}

extern "C" void kernel_launch(void* const* d_in, const int* in_sizes, int n_in,
                              void* d_out, int out_size, void* d_ws, size_t ws_size,
                              hipStream_t stream) {
    const float* x   = (const float*)d_in[0];
    const float* Wih = (const float*)d_in[1];
    const float* Whh = (const float*)d_in[2];
    const float* bih = (const float*)d_in[3];
    const float* bhh = (const float*)d_in[4];
    const float* Wfc = (const float*)d_in[5];
    const float* bfc = (const float*)d_in[6];

    float* out_newin = (float*)d_out;                 // [T*B] = 524288
    float* out_pred  = out_newin + Tlen * Bsz;        // [B*(T-1)] = 524032

    rnn_imp_kernel<<<Bsz / 2, 512, 0, stream>>>(x, Wih, Whh, bih, bhh, Wfc, bfc,
                                                out_newin, out_pred);
}

// Round 7
// 878.903 us; speedup vs baseline: 1.6353x; 1.6353x over previous
//
#include <hip/hip_runtime.h>

#define Bsz  256
#define Tlen 2048
#define Hdim 128

typedef __fp16 hf2 __attribute__((ext_vector_type(2)));
typedef __fp16 hf8 __attribute__((ext_vector_type(8)));
typedef float  f32x4 __attribute__((ext_vector_type(4)));

// Raw-HW transcendentals (VOP1, ~1 ulp). R12-verified win.
__device__ __forceinline__ float fexp2_(float x) {
    float r; asm("v_exp_f32 %0, %1" : "=v"(r) : "v"(x)); return r;
}
__device__ __forceinline__ float frcp_(float x) {
    float r; asm("v_rcp_f32 %0, %1" : "=v"(r) : "v"(x)); return r;
}

// pack 8 consecutive f32 into a v8f16 MFMA fragment slice
__device__ __forceinline__ hf8 pack8(const float* p) {
    union { hf2 h2[4]; hf8 h8; } u;
    u.h2[0] = __builtin_amdgcn_cvt_pkrtz(p[0], p[1]);
    u.h2[1] = __builtin_amdgcn_cvt_pkrtz(p[2], p[3]);
    u.h2[2] = __builtin_amdgcn_cvt_pkrtz(p[4], p[5]);
    u.h2[3] = __builtin_amdgcn_cvt_pkrtz(p[6], p[7]);
    return u.h8;
}
__device__ __forceinline__ hf8 bch8(float4 v) { return __builtin_bit_cast(hf8, v); }

#define MFMA(D, A, B) D = __builtin_amdgcn_mfma_f32_16x16x32_f16(A, B, D, 0, 0, 0)

struct Smem {
    float  x[Tlen];       // staged input row
    float  xh[Tlen];      // staged xh outputs
    __fp16 h[2][Hdim];    // double-buffered hidden state (f16)
};

// grid = 256 blocks (1 batch row each), block = 512 threads (8 waves).
// R30 = R28 champion (16 MFMA/wave/step, uniform-A, weights AGPR-native,
// one barrier/step, setprio antiphase) + SPLIT-K MFMA CHAINS.
// R29 post-mortem (2 rows in-wave, -61%): the 2nd row's 32 MFMAs cost
// +637 cyc = 20 cyc each, 2.5x the ubench pipe rate (8 cyc/SIMD) ->
// MFMAs are DEPENDENCY-STALLED, not pipe-limited: 4 accumulator chains
// with same-chain reuse distance 2-4 instrs < ~32 cyc result latency.
// Explains R25 flat (order can't fix chain count) and R27's non-linear
// payoff. Fix: split each gate's K=128 into two K=64 half-chains ->
// 8 independent chains x 2 MFMAs, reuse distance >= 6; combine at reg 0
// with one scalar v_add per gate. C_0 hoisted (no per-step acc zeroing).
// D3/D0 chains complete by instr 12 -> cur + r-sigmoid keep their early
// window. Numerics: f32 K-sum reassociation only.
// Session ledger: R24 fc->VALU -21% | R25 reorder flat | R26 diet flat |
// R27 16->12 MFMA -5% | R28 setprio +4% (894us champ) | R29 2-row -61%.
// Prediction: dur ~700-780us, MfmaUtil DROPS to ~34-40% (stall cycles
// gone), VALUBusy ~45-50%. If flat: issue-bound -> 894 is the floor.
// Layouts (R18-R21 HW-verified): B: lane l reg j = W[tile*16+(l&15)]
// [c*32+(l>>4)*8+j]; D: col = lane&15, reg 0 valid on all lanes (uniform A).
__global__ __launch_bounds__(512, 2)
void rnn_imp_kernel(const float* __restrict__ x,     // [B, T] (I=1)
                    const float* __restrict__ Wih,   // [384]
                    const float* __restrict__ Whh,   // [384, 128] gate-major (r,z,n)
                    const float* __restrict__ bih,   // [384]
                    const float* __restrict__ bhh,   // [384]
                    const float* __restrict__ Wfc,   // [128]
                    const float* __restrict__ bfc,   // [1]
                    float* __restrict__ out_newin,   // [T, B]
                    float* __restrict__ out_pred)    // [B, T-1]
{
    __shared__ __align__(128) Smem sm;

    const int tid  = threadIdx.x;
    const int b    = blockIdx.x;
    const int wave = tid >> 6;
    const int lane = tid & 63;
    const int m    = lane & 15;      // B/D column = unit-in-tile
    const int q    = lane >> 4;      // k-subchunk

    // stage x row (coalesced)
    for (int i = tid; i < Tlen; i += 512) sm.x[i] = x[b * Tlen + i];

    // ---- B fragments: W^T tiles (consumed only by MFMA -> AGPR-native) ----
    const int r0 = wave * 16 + m;            // unit row, gate r
    const int r1 = r0 + 128;                 // gate z
    const int r2 = r0 + 256;                 // gate n
    const int ko = q * 8;
    hf8 Br0, Br1, Br2, Br3, Bz0, Bz1, Bz2, Bz3,
        Bn0, Bn1, Bn2, Bn3, Bf0, Bf1, Bf2, Bf3;
    Br0 = pack8(Whh + r0 * Hdim + 0  + ko);  Br1 = pack8(Whh + r0 * Hdim + 32 + ko);
    Br2 = pack8(Whh + r0 * Hdim + 64 + ko);  Br3 = pack8(Whh + r0 * Hdim + 96 + ko);
    Bz0 = pack8(Whh + r1 * Hdim + 0  + ko);  Bz1 = pack8(Whh + r1 * Hdim + 32 + ko);
    Bz2 = pack8(Whh + r1 * Hdim + 64 + ko);  Bz3 = pack8(Whh + r1 * Hdim + 96 + ko);
    Bn0 = pack8(Whh + r2 * Hdim + 0  + ko);  Bn1 = pack8(Whh + r2 * Hdim + 32 + ko);
    Bn2 = pack8(Whh + r2 * Hdim + 64 + ko);  Bn3 = pack8(Whh + r2 * Hdim + 96 + ko);
    // Wfc in ALL columns: every lane's D3 reg 0 = xp
    Bf0 = pack8(Wfc + 0  + ko);  Bf1 = pack8(Wfc + 32 + ko);
    Bf2 = pack8(Wfc + 64 + ko);  Bf3 = pack8(Wfc + 96 + ko);

    // gate constants for this lane's column unit (valid on all lanes)
    const int ug = wave * 16 + m;
    const float wih_r = Wih[ug], wih_z = Wih[ug + 128], wih_n = Wih[ug + 256];
    const float bb_r = bih[ug]       + bhh[ug];
    const float bb_z = bih[ug + 128] + bhh[ug + 128];
    const float bi_n = bih[ug + 256];
    const float bh_n = bhh[ug + 256];
    const float bfc0 = bfc[0];

    // pre-scaled constants: fold log2e factors out of the per-step chain
    const float kNL2E = -1.44269504f;            // -log2(e)
    const float kP2L2E = 2.88539008f;            // 2*log2(e)
    const float wr_s  = kNL2E * wih_r;
    const float wz_s  = kNL2E * wih_z;
    const float wn_s  = kP2L2E * wih_n;
    const float bn_s  = kP2L2E * bi_n;
    // bias-seeded C operands for the LOW half-chains; zero for HIGH halves.
    // All hoisted -> persistent registers, no per-step accvgpr zero-inits.
    const f32x4 C_R = {bb_r, bb_r, bb_r, bb_r};
    const f32x4 C_Z = {bb_z, bb_z, bb_z, bb_z};
    const f32x4 C_N = {bh_n, bh_n, bh_n, bh_n};
    const f32x4 C_F = {bfc0, bfc0, bfc0, bfc0};
    const f32x4 C_0 = {0.0f, 0.0f, 0.0f, 0.0f};

    __syncthreads();                         // sm.x visible

    // ---- peeled t = 0: h = 0 => D = C-seed exactly; pure VALU ----
    float h_old;
    {
        float x0 = sm.x[0];
        float pr = wr_s * x0;
        float pz = wz_s * x0;
        float an = fmaf(wn_s, x0, bn_s);
        float r  = frcp_(1.0f + fexp2_(fmaf(kNL2E, bb_r, pr)));
        float z  = frcp_(1.0f + fexp2_(fmaf(kNL2E, bb_z, pz)));
        float rs = kP2L2E * r;
        float np = frcp_(fexp2_(fmaf(rs, bh_n, an)) + 1.0f);
        float w  = 1.0f - z;
        float hn = fmaf(-2.0f * w, np, w);   // hz = fma(z, 0, w) = w exactly
        h_old = hn;
        if (lane < 16) sm.h[1][ug] = (__fp16)hn;
        // sm.xh[0] never consumed (out_pred uses xh[1..]; newin at i=0 is raw x)
    }
    __syncthreads();

#pragma unroll 1
    for (int t = 1; t < Tlen; ++t) {
        // A fragments: every row = h (uniform-address broadcast reads)
        const float4* hp = (const float4*)sm.h[t & 1];
        hf8 A0 = bch8(hp[0 * 4 + q]);
        hf8 A1 = bch8(hp[1 * 4 + q]);
        hf8 A2 = bch8(hp[2 * 4 + q]);
        hf8 A3 = bch8(hp[3 * 4 + q]);

        // xt early: LDS latency hides under the MFMA block
        float xt = sm.x[t];

        __builtin_amdgcn_s_setprio(1);

        // 8 independent half-K chains, round-robin issue (reuse dist >= 6):
        // L chains take A0/A1 (k 0..63), H chains take A2/A3 (k 64..127).
        f32x4 D3L = __builtin_amdgcn_mfma_f32_16x16x32_f16(A0, Bf0, C_F, 0, 0, 0);
        f32x4 D0L = __builtin_amdgcn_mfma_f32_16x16x32_f16(A0, Br0, C_R, 0, 0, 0);
        f32x4 D1L = __builtin_amdgcn_mfma_f32_16x16x32_f16(A0, Bz0, C_Z, 0, 0, 0);
        f32x4 D2L = __builtin_amdgcn_mfma_f32_16x16x32_f16(A0, Bn0, C_N, 0, 0, 0);
        f32x4 D3H = __builtin_amdgcn_mfma_f32_16x16x32_f16(A2, Bf2, C_0, 0, 0, 0);
        f32x4 D0H = __builtin_amdgcn_mfma_f32_16x16x32_f16(A2, Br2, C_0, 0, 0, 0);
        f32x4 D1H = __builtin_amdgcn_mfma_f32_16x16x32_f16(A2, Bz2, C_0, 0, 0, 0);
        f32x4 D2H = __builtin_amdgcn_mfma_f32_16x16x32_f16(A2, Bn2, C_0, 0, 0, 0);
        MFMA(D3L, A1, Bf1);                  // D3L complete
        MFMA(D0L, A1, Br1);                  // D0L complete
        MFMA(D3H, A3, Bf3);                  // D3H complete
        MFMA(D0H, A3, Br3);                  // D0H complete

        // fc + r-gate ready: combine + cur + r-sigmoid under D1/D2 issue
        float xh  = D3L[0] + D3H[0];         // bfc0 pre-seeded in L
        float cur = (xt == 128.0f) ? xh : xt;
        float pr  = wr_s * cur;
        float pz  = wz_s * cur;
        float an  = fmaf(wn_s, cur, bn_s);
        float g0  = D0L[0] + D0H[0];
        float r   = frcp_(1.0f + fexp2_(fmaf(kNL2E, g0, pr)));
        float rs  = kP2L2E * r;              // hoisted off the D2->hn path

        MFMA(D1L, A1, Bz1);                  // D1L complete
        MFMA(D2L, A1, Bn1);                  // D2L complete
        MFMA(D1H, A3, Bz3);                  // D1H complete
        MFMA(D2H, A3, Bn3);                  // D2H complete

        __builtin_amdgcn_s_setprio(0);       // tail runs at low priority

        // gates: unpredicated on all 64 lanes (q-copies compute identical hn)
        float g1  = D1L[0] + D1H[0];
        float g2  = D2L[0] + D2H[0];
        float z   = frcp_(1.0f + fexp2_(fmaf(kNL2E, g1, pz)));
        float np  = frcp_(fexp2_(fmaf(rs, g2, an)) + 1.0f);     // n = 1 - 2*np
        float w   = 1.0f - z;
        float m2w = -2.0f * w;               // parallel to hz, off the chain
        float hz  = fmaf(z, h_old, w);
        float hn  = fmaf(m2w, np, hz);       // (1-z)*n + z*h
        h_old = hn;

        if (lane < 16) sm.h[(t + 1) & 1][ug] = (__fp16)hn;
        if (tid == 0)  sm.xh[t] = xh;
        __syncthreads();
    }

    // bulk flush; cur reconstructed from pristine x + xh
    for (int i = tid; i < Tlen; i += 512) {
        float xv = sm.x[i];
        float cv = ((xv == 128.0f) && (i != 0)) ? sm.xh[i] : xv;
        out_newin[i * Bsz + b] = cv;
    }
    for (int i = tid; i < Tlen - 1; i += 512)
        out_pred[b * (Tlen - 1) + i] = sm.xh[i + 1];
}

extern "C" void kernel_launch(void* const* d_in, const int* in_sizes, int n_in,
                              void* d_out, int out_size, void* d_ws, size_t ws_size,
                              hipStream_t stream) {
    const float* x   = (const float*)d_in[0];
    const float* Wih = (const float*)d_in[1];
    const float* Whh = (const float*)d_in[2];
    const float* bih = (const float*)d_in[3];
    const float* bhh = (const float*)d_in[4];
    const float* Wfc = (const float*)d_in[5];
    const float* bfc = (const float*)d_in[6];

    float* out_newin = (float*)d_out;                 // [T*B] = 524288
    float* out_pred  = out_newin + Tlen * Bsz;        // [B*(T-1)] = 524032

    rnn_imp_kernel<<<Bsz, 512, 0, stream>>>(x, Wih, Whh, bih, bhh, Wfc, bfc,
                                            out_newin, out_pred);
}